// Round 1
// 454.784 us; speedup vs baseline: 1.2827x; 1.2827x over previous
//
#include <hip/hip_runtime.h>
#include <cstdint>

#define B_   64
#define H_   56
#define W_   56
#define C_   128
#define WSZ  7
#define TT   49
#define NN   3136            // H*W
#define MM   (B_ * NN)       // 200704
#define SCALE 0.17677669529663687f

typedef short bf16x8 __attribute__((ext_vector_type(8)));   // 8 bf16 (4 VGPRs)
typedef float f32x4  __attribute__((ext_vector_type(4)));
typedef unsigned short u16;

__device__ __forceinline__ float bf2f(u16 u) {
    return __uint_as_float(((unsigned int)u) << 16);
}
__device__ __forceinline__ u16 f2bf(float f) {
    unsigned int u = __float_as_uint(f);
    u += 0x7FFFu + ((u >> 16) & 1u);   // round-to-nearest-even
    return (u16)(u >> 16);
}

// ---------------------------------------------------------------------------
// KA: fused qkv-GEMM + windowed attention, MFMA. One block per (b, window).
// LDS arena: [0]=x window, [1]=q, [2]=k, [3]=v (each 64x136 u16 = 17,408 B,
// total 69,632 B -> 2 blocks/CU). P (4 heads x 64x64 bf16 = 32,768 B)
// overlays the q+k slabs after q/k frags are in registers (barrier-protected).
// w_qkv B-fragments are converted f32->bf16 straight from global (L2-res).
// v is now stored to global in IMAGE layout (B,H,W,C) bf16 so KB needs no
// windowed-index div/mod.
// ---------------------------------------------------------------------------
__global__ __launch_bounds__(256) void ka_fused(
    const float* __restrict__ x, const float* __restrict__ wqkv,
    u16* __restrict__ vout, float* __restrict__ out)
{
    __shared__ u16 arena[4][64][136];
    u16* ps_ = &arena[1][0][0];     // 32,768 B overlay on q+k slabs (34,816 B)

    const int t   = threadIdx.x;
    const int blk = blockIdx.x;
    const int b_  = blk >> 6, wr = blk & 63;
    const int qy  = wr >> 3, qx = wr & 7;
    const int wave = t >> 6, lane = t & 63, lr = lane & 15, quad = lane >> 4;

    // ---- phase 0: stage x window -> arena[0] (bf16), zero pad rows ----
    for (int i = t; i < 64 * 32; i += 256) {
        int tok = i >> 5, c4 = (i & 31) * 4;
        ushort4 u4 = {0, 0, 0, 0};
        if (tok < TT) {
            int hh = qy * WSZ + tok / WSZ, ww = qx * WSZ + tok % WSZ;
            float4 f = *(const float4*)&x[((size_t)b_ * NN + hh * W_ + ww) * C_ + c4];
            u4.x = f2bf(f.x); u4.y = f2bf(f.y);
            u4.z = f2bf(f.z); u4.w = f2bf(f.w);
        }
        *(ushort4*)&arena[0][tok][c4] = u4;
    }
    __syncthreads();

    // ---- phase 1: q/k/v = x @ w_chunk^T; B-frags direct from global.
    // Each wave owns output cols [half*64+wave*16, +16) -> no barriers. ----
    for (int ch = 0; ch < 3; ch++) {
        const float mul = (ch == 0) ? SCALE : 1.0f;
        u16 (*dst)[136] = arena[1 + ch];
#pragma unroll
        for (int half = 0; half < 2; half++) {
            const float* wrow =
                &wqkv[(size_t)(ch * 128 + half * 64 + wave * 16 + lr) * C_];
            f32x4 acc[4];
#pragma unroll
            for (int mi = 0; mi < 4; mi++) acc[mi] = {0.f, 0.f, 0.f, 0.f};
#pragma unroll
            for (int kk = 0; kk < 4; kk++) {
                float4 f0 = *(const float4*)&wrow[kk * 32 + quad * 8];
                float4 f1 = *(const float4*)&wrow[kk * 32 + quad * 8 + 4];
                bf16x8 bfr;
                bfr[0] = (short)f2bf(f0.x); bfr[1] = (short)f2bf(f0.y);
                bfr[2] = (short)f2bf(f0.z); bfr[3] = (short)f2bf(f0.w);
                bfr[4] = (short)f2bf(f1.x); bfr[5] = (short)f2bf(f1.y);
                bfr[6] = (short)f2bf(f1.z); bfr[7] = (short)f2bf(f1.w);
#pragma unroll
                for (int mi = 0; mi < 4; mi++) {
                    bf16x8 afr = *(const bf16x8*)&arena[0][mi * 16 + lr][kk * 32 + quad * 8];
                    acc[mi] = __builtin_amdgcn_mfma_f32_16x16x32_bf16(
                        afr, bfr, acc[mi], 0, 0, 0);
                }
            }
#pragma unroll
            for (int mi = 0; mi < 4; mi++) {
#pragma unroll
                for (int r = 0; r < 4; r++) {
                    int tok = mi * 16 + quad * 4 + r;
                    int col = half * 64 + wave * 16 + lr;
                    u16 bv = f2bf(acc[mi][r] * mul);
                    dst[tok][col] = bv;
                    if (ch == 2 && tok < TT) {
                        int hh2 = qy * WSZ + tok / WSZ;
                        int ww2 = qx * WSZ + tok % WSZ;
                        vout[((size_t)b_ * NN + hh2 * W_ + ww2) * C_ + col] = bv;
                    }
                }
            }
        }
    }
    __syncthreads();   // publish q/k/v to all waves

    // ---- phase 2: attention, wave = head ----
    const int h = wave;
    bf16x8 qf[4], kf[4];
#pragma unroll
    for (int mi = 0; mi < 4; mi++) {
        qf[mi] = *(const bf16x8*)&arena[1][mi * 16 + lr][h * 32 + quad * 8];
        kf[mi] = *(const bf16x8*)&arena[2][mi * 16 + lr][h * 32 + quad * 8];
    }
    __syncthreads();   // all waves hold q/k frags -> ps overlay now safe

    f32x4 s[4][4];
#pragma unroll
    for (int mi = 0; mi < 4; mi++)
#pragma unroll
        for (int nj = 0; nj < 4; nj++) s[mi][nj] = {0.f, 0.f, 0.f, 0.f};
#pragma unroll
    for (int mi = 0; mi < 4; mi++)
#pragma unroll
        for (int nj = 0; nj < 4; nj++)
            s[mi][nj] = __builtin_amdgcn_mfma_f32_16x16x32_bf16(
                qf[mi], kf[nj], s[mi][nj], 0, 0, 0);

    // mask pad key columns j = 48 + lr, lr >= 1
    if (lr >= 1) {
#pragma unroll
        for (int mi = 0; mi < 4; mi++)
#pragma unroll
            for (int r = 0; r < 4; r++) s[mi][3][r] = -1e30f;
    }

    float rsum[4][4];
#pragma unroll
    for (int mi = 0; mi < 4; mi++) {
#pragma unroll
        for (int r = 0; r < 4; r++) {
            float mx = fmaxf(fmaxf(s[mi][0][r], s[mi][1][r]),
                             fmaxf(s[mi][2][r], s[mi][3][r]));
#pragma unroll
            for (int off = 1; off < 16; off <<= 1)
                mx = fmaxf(mx, __shfl_xor(mx, off));
            float sum = 0.f;
#pragma unroll
            for (int nj = 0; nj < 4; nj++) {
                float p = __expf(s[mi][nj][r] - mx);
                s[mi][nj][r] = p;
                sum += p;
            }
#pragma unroll
            for (int off = 1; off < 16; off <<= 1)
                sum += __shfl_xor(sum, off);
            rsum[mi][r] = sum;
        }
    }

    // P: C-layout -> LDS (overlay, stride 64) -> A-layout (intra-wave)
#pragma unroll
    for (int mi = 0; mi < 4; mi++)
#pragma unroll
        for (int nj = 0; nj < 4; nj++)
#pragma unroll
            for (int r = 0; r < 4; r++)
                ps_[((h * 64) + mi * 16 + quad * 4 + r) * 64 + nj * 16 + lr] =
                    f2bf(s[mi][nj][r]);

    f32x4 o[4][2];
#pragma unroll
    for (int mi = 0; mi < 4; mi++)
#pragma unroll
        for (int nv = 0; nv < 2; nv++) o[mi][nv] = {0.f, 0.f, 0.f, 0.f};

#pragma unroll
    for (int kt = 0; kt < 2; kt++) {
        bf16x8 pf[4];
#pragma unroll
        for (int mi = 0; mi < 4; mi++)
            pf[mi] = *(const bf16x8*)&ps_[((h * 64) + mi * 16 + lr) * 64 +
                                          kt * 32 + quad * 8];
        bf16x8 vf[2];
#pragma unroll
        for (int nv = 0; nv < 2; nv++) {
            bf16x8 tmp;
#pragma unroll
            for (int jj = 0; jj < 8; jj++)
                tmp[jj] = (short)arena[3][kt * 32 + quad * 8 + jj][h * 32 + nv * 16 + lr];
            vf[nv] = tmp;
        }
#pragma unroll
        for (int mi = 0; mi < 4; mi++)
#pragma unroll
            for (int nv = 0; nv < 2; nv++)
                o[mi][nv] = __builtin_amdgcn_mfma_f32_16x16x32_bf16(
                    pf[mi], vf[nv], o[mi][nv], 0, 0, 0);
    }

#pragma unroll
    for (int mi = 0; mi < 4; mi++) {
#pragma unroll
        for (int r = 0; r < 4; r++) {
            int i = mi * 16 + quad * 4 + r;
            if (i < TT) {
                int hh = qy * WSZ + i / WSZ, ww = qx * WSZ + i % WSZ;
                size_t orow = (size_t)b_ * NN + hh * W_ + ww;
                float inv = 1.f / rsum[mi][r];
#pragma unroll
                for (int nv = 0; nv < 2; nv++)
                    out[orow * C_ + h * 32 + nv * 16 + lr] = o[mi][nv][r] * inv;
            }
        }
    }
}

// ---------------------------------------------------------------------------
// KB v2: depthwise 3x3 conv on bf16 v (IMAGE layout B,H,W,C) + f32 bias,
// accumulate f32 into d_out (B,N,C).
// One thread = 8 contiguous channels of one (b,h,w) position:
//   - 16 threads/position x 16 positions/block (256 thr)
//   - per tap: one coalesced 16-B bf16x8 load + 8 unpack/FMA
//   - 72 conv weights + 8 bias hoisted to registers (18x/2x float4, L1-res)
//   - output RMW as 2x float4
// Replaces the VALU-bound scalar version (78% VALUBusy, 14% HBM) with a
// memory-bound one (~257 MB ideal traffic).
// ---------------------------------------------------------------------------
__global__ __launch_bounds__(256) void kb_lim(
    const u16* __restrict__ v, const float* __restrict__ wlim,
    const float* __restrict__ blim, float* __restrict__ out)
{
    const int t   = threadIdx.x;
    const int pos = blockIdx.x * 16 + (t >> 4);
    const int c0  = (t & 15) * 8;
    const int b_  = pos / NN;
    const int rem = pos - b_ * NN;
    const int hh  = rem / W_;
    const int ww  = rem - hh * W_;

    // weights for channels [c0, c0+8): 72 contiguous floats, 16B-aligned
    float w72[72];
    {
        const float* wp = &wlim[c0 * 9];
#pragma unroll
        for (int i = 0; i < 18; i++) {
            float4 f = *(const float4*)&wp[i * 4];
            w72[i * 4 + 0] = f.x; w72[i * 4 + 1] = f.y;
            w72[i * 4 + 2] = f.z; w72[i * 4 + 3] = f.w;
        }
    }
    float acc[8];
    {
        float4 b0 = *(const float4*)&blim[c0];
        float4 b1 = *(const float4*)&blim[c0 + 4];
        acc[0] = b0.x; acc[1] = b0.y; acc[2] = b0.z; acc[3] = b0.w;
        acc[4] = b1.x; acc[5] = b1.y; acc[6] = b1.z; acc[7] = b1.w;
    }

    const u16* vbase = &v[(size_t)b_ * NN * C_ + c0];
#pragma unroll
    for (int dy = -1; dy <= 1; dy++) {
        int y = hh + dy;
        bool yok = (unsigned)y < (unsigned)H_;
#pragma unroll
        for (int dx = -1; dx <= 1; dx++) {
            int x2 = ww + dx;
            bool ok = yok && ((unsigned)x2 < (unsigned)W_);
            bf16x8 vv = {0, 0, 0, 0, 0, 0, 0, 0};
            if (ok) vv = *(const bf16x8*)&vbase[(size_t)(y * W_ + x2) * C_];
            const int tap = (dy + 1) * 3 + (dx + 1);
#pragma unroll
            for (int j = 0; j < 8; j++)
                acc[j] += bf2f((u16)vv[j]) * w72[j * 9 + tap];
        }
    }

    float* op = &out[(size_t)pos * C_ + c0];
    float4 o0 = *(const float4*)&op[0];
    float4 o1 = *(const float4*)&op[4];
    o0.x += acc[0]; o0.y += acc[1]; o0.z += acc[2]; o0.w += acc[3];
    o1.x += acc[4]; o1.y += acc[5]; o1.z += acc[6]; o1.w += acc[7];
    *(float4*)&op[0] = o0;
    *(float4*)&op[4] = o1;
}

// ---------------------------------------------------------------------------
// KC: out = y @ w_proj^T + b_proj, MFMA gemm_bt, f32 I/O staged to bf16.
// FIXED: acc[4][4] / ni 0..3 -> each n-wave covers its FULL 64 columns
// (round 1/3 bug: acc[4][2] left cols [32,64)+[96,128) unwritten).
// ---------------------------------------------------------------------------
__global__ __launch_bounds__(256) void kc_proj(
    float* __restrict__ y, const float* __restrict__ wproj,
    const float* __restrict__ bproj)
{
    __shared__ u16 As[128][72];
    __shared__ u16 Ws[128][72];
    const int t    = threadIdx.x;
    const int m0   = blockIdx.x * 128;
    const int wave = t >> 6, lane = t & 63, lr = lane & 15, quad = lane >> 4;
    const int wm = (wave >> 1) * 64, wn = (wave & 1) * 64;

    f32x4 acc[4][4];
#pragma unroll
    for (int mi = 0; mi < 4; mi++)
#pragma unroll
        for (int ni = 0; ni < 4; ni++) acc[mi][ni] = {0.f, 0.f, 0.f, 0.f};

#pragma unroll
    for (int kt = 0; kt < 2; kt++) {
        const int k0 = kt * 64;
#pragma unroll
        for (int p = 0; p < 8; p++) {
            int e   = p * 256 + t;
            int row = e >> 4;
            int col = (e & 15) * 4;
            float4 fa = *(const float4*)&y[(size_t)(m0 + row) * C_ + k0 + col];
            ushort4 ua;
            ua.x = f2bf(fa.x); ua.y = f2bf(fa.y);
            ua.z = f2bf(fa.z); ua.w = f2bf(fa.w);
            *(ushort4*)&As[row][col] = ua;
            float4 fw = *(const float4*)&wproj[(size_t)row * C_ + k0 + col];
            ushort4 uw;
            uw.x = f2bf(fw.x); uw.y = f2bf(fw.y);
            uw.z = f2bf(fw.z); uw.w = f2bf(fw.w);
            *(ushort4*)&Ws[row][col] = uw;
        }
        __syncthreads();
#pragma unroll
        for (int kk = 0; kk < 2; kk++) {
            bf16x8 a[4], b[4];
#pragma unroll
            for (int mi = 0; mi < 4; mi++)
                a[mi] = *(const bf16x8*)&As[wm + mi * 16 + lr][kk * 32 + quad * 8];
#pragma unroll
            for (int ni = 0; ni < 4; ni++)
                b[ni] = *(const bf16x8*)&Ws[wn + ni * 16 + lr][kk * 32 + quad * 8];
#pragma unroll
            for (int mi = 0; mi < 4; mi++)
#pragma unroll
                for (int ni = 0; ni < 4; ni++)
                    acc[mi][ni] = __builtin_amdgcn_mfma_f32_16x16x32_bf16(
                        a[mi], b[ni], acc[mi][ni], 0, 0, 0);
        }
        if (kt == 0) __syncthreads();
    }

#pragma unroll
    for (int mi = 0; mi < 4; mi++) {
#pragma unroll
        for (int r = 0; r < 4; r++) {
            int m = m0 + wm + mi * 16 + quad * 4 + r;
#pragma unroll
            for (int ni = 0; ni < 4; ni++) {
                int c = wn + ni * 16 + lr;
                y[(size_t)m * C_ + c] = acc[mi][ni][r] + bproj[c];
            }
        }
    }
}

extern "C" void kernel_launch(void* const* d_in, const int* in_sizes, int n_in,
                              void* d_out, int out_size, void* d_ws, size_t ws_size,
                              hipStream_t stream)
{
    const float* x     = (const float*)d_in[0];
    const float* wqkv  = (const float*)d_in[1];
    const float* wlim  = (const float*)d_in[2];
    const float* blim  = (const float*)d_in[3];
    const float* wproj = (const float*)d_in[4];
    const float* bproj = (const float*)d_in[5];
    float* out = (float*)d_out;
    u16*   v   = (u16*)d_ws;            // 51.4 MB (round-2-proven footprint)

    ka_fused<<<dim3(B_ * 64), 256, 0, stream>>>(x, wqkv, v, out);
    kb_lim  <<<dim3(MM / 16), 256, 0, stream>>>(v, wlim, blim, out);
    kc_proj <<<dim3(MM / 128), 256, 0, stream>>>(out, wproj, bproj);
}

// Round 2
// 440.122 us; speedup vs baseline: 1.3254x; 1.0333x over previous
//
#include <hip/hip_runtime.h>
#include <cstdint>

#define B_   64
#define H_   56
#define W_   56
#define C_   128
#define WSZ  7
#define TT   49
#define NN   3136            // H*W
#define MM   (B_ * NN)       // 200704
#define SCALE 0.17677669529663687f

typedef short bf16x8 __attribute__((ext_vector_type(8)));   // 8 bf16 (4 VGPRs)
typedef short bf16x4 __attribute__((ext_vector_type(4)));   // 8B (2 VGPRs)
typedef float f32x4  __attribute__((ext_vector_type(4)));
typedef unsigned short u16;

__device__ __forceinline__ float bf2f(u16 u) {
    return __uint_as_float(((unsigned int)u) << 16);
}
__device__ __forceinline__ u16 f2bf(float f) {
    unsigned int u = __float_as_uint(f);
    u += 0x7FFFu + ((u >> 16) & 1u);   // round-to-nearest-even
    return (u16)(u >> 16);
}

// ---------------------------------------------------------------------------
// KA v3: fused qkv-GEMM + windowed attention, MFMA. One block per (b,window).
// LDS: 3 slabs (52,480 B -> 3 blocks/CU = 12 waves/CU, was 2/8):
//   xq[64][136]  x window, later overwritten by q (x dead after q-MFMA)
//   ks[64][136]  k
//   vs[64][138]  v  (stride 138: quad-row step == 8 banks -> transpose reads
//                    conflict-free; was 8-way at stride 136)
// P overlay: 256 rows x 68 u16 = 34,816 B == xq+ks exactly (barrier-protected
// after q/k frags are register-resident). Stride 68 -> stores hit 32 distinct
// dwords (conflict-free, was 4-way) and reads are 2x ds_read_b64 with
// perfectly even bank distribution (was 16-way ds_read_b128 at stride 64).
// Order: stage x -> k -> v(+global) -> q accs in regs -> barrier -> q over x.
// ---------------------------------------------------------------------------
__global__ __launch_bounds__(256, 3) void ka_fused(
    const float* __restrict__ x, const float* __restrict__ wqkv,
    u16* __restrict__ vout, float* __restrict__ out)
{
    __shared__ u16 lds[26240];                       // 52,480 B
    u16 (*xq)[136] = (u16(*)[136])&lds[0];           // x, later q
    u16 (*ks)[136] = (u16(*)[136])&lds[8704];        // k
    u16 (*vs)[138] = (u16(*)[138])&lds[17408];       // v
    u16* ps_ = &lds[0];                              // P: 256 x 68 u16 overlay

    const int t   = threadIdx.x;
    const int blk = blockIdx.x;
    const int b_  = blk >> 6, wr = blk & 63;
    const int qy  = wr >> 3, qx = wr & 7;
    const int wave = t >> 6, lane = t & 63, lr = lane & 15, quad = lane >> 4;

    // ---- phase 0: stage x window -> xq (bf16), zero pad rows ----
    for (int i = t; i < 64 * 32; i += 256) {
        int tok = i >> 5, c4 = (i & 31) * 4;
        ushort4 u4 = {0, 0, 0, 0};
        if (tok < TT) {
            int hh = qy * WSZ + tok / WSZ, ww = qx * WSZ + tok % WSZ;
            float4 f = *(const float4*)&x[((size_t)b_ * NN + hh * W_ + ww) * C_ + c4];
            u4.x = f2bf(f.x); u4.y = f2bf(f.y);
            u4.z = f2bf(f.z); u4.w = f2bf(f.w);
        }
        *(ushort4*)&xq[tok][c4] = u4;
    }
    __syncthreads();

    // ---- phase 1a: k (ch=1) -> ks, v (ch=2) -> vs + global.
    // Each wave owns output cols [half*64+wave*16, +16) -> no barriers. ----
#pragma unroll
    for (int cc = 0; cc < 2; cc++) {
        const int ch = 1 + cc;
        u16* dstbase = cc ? &vs[0][0] : &ks[0][0];
        const int dstride = cc ? 138 : 136;
#pragma unroll
        for (int half = 0; half < 2; half++) {
            const float* wrow =
                &wqkv[(size_t)(ch * 128 + half * 64 + wave * 16 + lr) * C_];
            f32x4 acc[4];
#pragma unroll
            for (int mi = 0; mi < 4; mi++) acc[mi] = {0.f, 0.f, 0.f, 0.f};
#pragma unroll
            for (int kk = 0; kk < 4; kk++) {
                float4 f0 = *(const float4*)&wrow[kk * 32 + quad * 8];
                float4 f1 = *(const float4*)&wrow[kk * 32 + quad * 8 + 4];
                bf16x8 bfr;
                bfr[0] = (short)f2bf(f0.x); bfr[1] = (short)f2bf(f0.y);
                bfr[2] = (short)f2bf(f0.z); bfr[3] = (short)f2bf(f0.w);
                bfr[4] = (short)f2bf(f1.x); bfr[5] = (short)f2bf(f1.y);
                bfr[6] = (short)f2bf(f1.z); bfr[7] = (short)f2bf(f1.w);
#pragma unroll
                for (int mi = 0; mi < 4; mi++) {
                    bf16x8 afr = *(const bf16x8*)&xq[mi * 16 + lr][kk * 32 + quad * 8];
                    acc[mi] = __builtin_amdgcn_mfma_f32_16x16x32_bf16(
                        afr, bfr, acc[mi], 0, 0, 0);
                }
            }
#pragma unroll
            for (int mi = 0; mi < 4; mi++) {
#pragma unroll
                for (int r = 0; r < 4; r++) {
                    int tok = mi * 16 + quad * 4 + r;
                    int col = half * 64 + wave * 16 + lr;
                    u16 bv = f2bf(acc[mi][r]);
                    dstbase[tok * dstride + col] = bv;
                    if (cc == 1 && tok < TT) {
                        int hh2 = qy * WSZ + tok / WSZ;
                        int ww2 = qx * WSZ + tok % WSZ;
                        vout[((size_t)b_ * NN + hh2 * W_ + ww2) * C_ + col] = bv;
                    }
                }
            }
        }
    }

    // ---- phase 1b: q accumulators in registers (x still live) ----
    f32x4 qacc[2][4];
#pragma unroll
    for (int half = 0; half < 2; half++)
#pragma unroll
        for (int mi = 0; mi < 4; mi++) qacc[half][mi] = {0.f, 0.f, 0.f, 0.f};
#pragma unroll
    for (int half = 0; half < 2; half++) {
        const float* wrow = &wqkv[(size_t)(half * 64 + wave * 16 + lr) * C_];
#pragma unroll
        for (int kk = 0; kk < 4; kk++) {
            float4 f0 = *(const float4*)&wrow[kk * 32 + quad * 8];
            float4 f1 = *(const float4*)&wrow[kk * 32 + quad * 8 + 4];
            bf16x8 bfr;
            bfr[0] = (short)f2bf(f0.x); bfr[1] = (short)f2bf(f0.y);
            bfr[2] = (short)f2bf(f0.z); bfr[3] = (short)f2bf(f0.w);
            bfr[4] = (short)f2bf(f1.x); bfr[5] = (short)f2bf(f1.y);
            bfr[6] = (short)f2bf(f1.z); bfr[7] = (short)f2bf(f1.w);
#pragma unroll
            for (int mi = 0; mi < 4; mi++) {
                bf16x8 afr = *(const bf16x8*)&xq[mi * 16 + lr][kk * 32 + quad * 8];
                qacc[half][mi] = __builtin_amdgcn_mfma_f32_16x16x32_bf16(
                    afr, bfr, qacc[half][mi], 0, 0, 0);
            }
        }
    }
    __syncthreads();   // all x reads done; k/v published

    // write q (scaled) over the x slab
#pragma unroll
    for (int half = 0; half < 2; half++)
#pragma unroll
        for (int mi = 0; mi < 4; mi++)
#pragma unroll
            for (int r = 0; r < 4; r++)
                xq[mi * 16 + quad * 4 + r][half * 64 + wave * 16 + lr] =
                    f2bf(qacc[half][mi][r] * SCALE);
    __syncthreads();   // q published

    // ---- phase 2: attention, wave = head ----
    const int h = wave;
    bf16x8 qf[4], kf[4];
#pragma unroll
    for (int mi = 0; mi < 4; mi++) {
        qf[mi] = *(const bf16x8*)&xq[mi * 16 + lr][h * 32 + quad * 8];
        kf[mi] = *(const bf16x8*)&ks[mi * 16 + lr][h * 32 + quad * 8];
    }
    __syncthreads();   // all waves hold q/k frags -> ps overlay now safe

    f32x4 s[4][4];
#pragma unroll
    for (int mi = 0; mi < 4; mi++)
#pragma unroll
        for (int nj = 0; nj < 4; nj++) s[mi][nj] = {0.f, 0.f, 0.f, 0.f};
#pragma unroll
    for (int mi = 0; mi < 4; mi++)
#pragma unroll
        for (int nj = 0; nj < 4; nj++)
            s[mi][nj] = __builtin_amdgcn_mfma_f32_16x16x32_bf16(
                qf[mi], kf[nj], s[mi][nj], 0, 0, 0);

    // mask pad key columns j = 48 + lr, lr >= 1
    if (lr >= 1) {
#pragma unroll
        for (int mi = 0; mi < 4; mi++)
#pragma unroll
            for (int r = 0; r < 4; r++) s[mi][3][r] = -1e30f;
    }

    float rsum[4][4];
#pragma unroll
    for (int mi = 0; mi < 4; mi++) {
#pragma unroll
        for (int r = 0; r < 4; r++) {
            float mx = fmaxf(fmaxf(s[mi][0][r], s[mi][1][r]),
                             fmaxf(s[mi][2][r], s[mi][3][r]));
#pragma unroll
            for (int off = 1; off < 16; off <<= 1)
                mx = fmaxf(mx, __shfl_xor(mx, off));
            float sum = 0.f;
#pragma unroll
            for (int nj = 0; nj < 4; nj++) {
                float p = __expf(s[mi][nj][r] - mx);
                s[mi][nj][r] = p;
                sum += p;
            }
#pragma unroll
            for (int off = 1; off < 16; off <<= 1)
                sum += __shfl_xor(sum, off);
            rsum[mi][r] = sum;
        }
    }

    // P: C-layout -> LDS (overlay, stride 68 = conflict-free) -> A-layout
#pragma unroll
    for (int mi = 0; mi < 4; mi++)
#pragma unroll
        for (int nj = 0; nj < 4; nj++)
#pragma unroll
            for (int r = 0; r < 4; r++)
                ps_[((h * 64) + mi * 16 + quad * 4 + r) * 68 + nj * 16 + lr] =
                    f2bf(s[mi][nj][r]);

    f32x4 o[4][2];
#pragma unroll
    for (int mi = 0; mi < 4; mi++)
#pragma unroll
        for (int nv = 0; nv < 2; nv++) o[mi][nv] = {0.f, 0.f, 0.f, 0.f};

#pragma unroll
    for (int kt = 0; kt < 2; kt++) {
        bf16x8 pf[4];
#pragma unroll
        for (int mi = 0; mi < 4; mi++) {
            const u16* pp = &ps_[((h * 64) + mi * 16 + lr) * 68 + kt * 32 + quad * 8];
            bf16x4 lo = *(const bf16x4*)&pp[0];    // 8B-aligned (rows stride 136B)
            bf16x4 hi = *(const bf16x4*)&pp[4];
            bf16x8 f;
            f[0] = lo[0]; f[1] = lo[1]; f[2] = lo[2]; f[3] = lo[3];
            f[4] = hi[0]; f[5] = hi[1]; f[6] = hi[2]; f[7] = hi[3];
            pf[mi] = f;
        }
        bf16x8 vf[2];
#pragma unroll
        for (int nv = 0; nv < 2; nv++) {
            bf16x8 tmp;
#pragma unroll
            for (int jj = 0; jj < 8; jj++)
                tmp[jj] = (short)vs[kt * 32 + quad * 8 + jj][h * 32 + nv * 16 + lr];
            vf[nv] = tmp;
        }
#pragma unroll
        for (int mi = 0; mi < 4; mi++)
#pragma unroll
            for (int nv = 0; nv < 2; nv++)
                o[mi][nv] = __builtin_amdgcn_mfma_f32_16x16x32_bf16(
                    pf[mi], vf[nv], o[mi][nv], 0, 0, 0);
    }

#pragma unroll
    for (int mi = 0; mi < 4; mi++) {
#pragma unroll
        for (int r = 0; r < 4; r++) {
            int i = mi * 16 + quad * 4 + r;
            if (i < TT) {
                int hh = qy * WSZ + i / WSZ, ww = qx * WSZ + i % WSZ;
                size_t orow = (size_t)b_ * NN + hh * W_ + ww;
                float inv = 1.f / rsum[mi][r];
#pragma unroll
                for (int nv = 0; nv < 2; nv++)
                    out[orow * C_ + h * 32 + nv * 16 + lr] = o[mi][nv][r] * inv;
            }
        }
    }
}

// ---------------------------------------------------------------------------
// KB v2: depthwise 3x3 conv on bf16 v (IMAGE layout B,H,W,C) + f32 bias,
// accumulate f32 into d_out (B,N,C). One thread = 8 channels of one position.
// ---------------------------------------------------------------------------
__global__ __launch_bounds__(256) void kb_lim(
    const u16* __restrict__ v, const float* __restrict__ wlim,
    const float* __restrict__ blim, float* __restrict__ out)
{
    const int t   = threadIdx.x;
    const int pos = blockIdx.x * 16 + (t >> 4);
    const int c0  = (t & 15) * 8;
    const int b_  = pos / NN;
    const int rem = pos - b_ * NN;
    const int hh  = rem / W_;
    const int ww  = rem - hh * W_;

    float w72[72];
    {
        const float* wp = &wlim[c0 * 9];
#pragma unroll
        for (int i = 0; i < 18; i++) {
            float4 f = *(const float4*)&wp[i * 4];
            w72[i * 4 + 0] = f.x; w72[i * 4 + 1] = f.y;
            w72[i * 4 + 2] = f.z; w72[i * 4 + 3] = f.w;
        }
    }
    float acc[8];
    {
        float4 b0 = *(const float4*)&blim[c0];
        float4 b1 = *(const float4*)&blim[c0 + 4];
        acc[0] = b0.x; acc[1] = b0.y; acc[2] = b0.z; acc[3] = b0.w;
        acc[4] = b1.x; acc[5] = b1.y; acc[6] = b1.z; acc[7] = b1.w;
    }

    const u16* vbase = &v[(size_t)b_ * NN * C_ + c0];
#pragma unroll
    for (int dy = -1; dy <= 1; dy++) {
        int y = hh + dy;
        bool yok = (unsigned)y < (unsigned)H_;
#pragma unroll
        for (int dx = -1; dx <= 1; dx++) {
            int x2 = ww + dx;
            bool ok = yok && ((unsigned)x2 < (unsigned)W_);
            bf16x8 vv = {0, 0, 0, 0, 0, 0, 0, 0};
            if (ok) vv = *(const bf16x8*)&vbase[(size_t)(y * W_ + x2) * C_];
            const int tap = (dy + 1) * 3 + (dx + 1);
#pragma unroll
            for (int j = 0; j < 8; j++)
                acc[j] += bf2f((u16)vv[j]) * w72[j * 9 + tap];
        }
    }

    float* op = &out[(size_t)pos * C_ + c0];
    float4 o0 = *(const float4*)&op[0];
    float4 o1 = *(const float4*)&op[4];
    o0.x += acc[0]; o0.y += acc[1]; o0.z += acc[2]; o0.w += acc[3];
    o1.x += acc[4]; o1.y += acc[5]; o1.z += acc[6]; o1.w += acc[7];
    *(float4*)&op[0] = o0;
    *(float4*)&op[4] = o1;
}

// ---------------------------------------------------------------------------
// KC: out = y @ w_proj^T + b_proj, MFMA gemm_bt, f32 I/O staged to bf16.
// ---------------------------------------------------------------------------
__global__ __launch_bounds__(256) void kc_proj(
    float* __restrict__ y, const float* __restrict__ wproj,
    const float* __restrict__ bproj)
{
    __shared__ u16 As[128][72];
    __shared__ u16 Ws[128][72];
    const int t    = threadIdx.x;
    const int m0   = blockIdx.x * 128;
    const int wave = t >> 6, lane = t & 63, lr = lane & 15, quad = lane >> 4;
    const int wm = (wave >> 1) * 64, wn = (wave & 1) * 64;

    f32x4 acc[4][4];
#pragma unroll
    for (int mi = 0; mi < 4; mi++)
#pragma unroll
        for (int ni = 0; ni < 4; ni++) acc[mi][ni] = {0.f, 0.f, 0.f, 0.f};

#pragma unroll
    for (int kt = 0; kt < 2; kt++) {
        const int k0 = kt * 64;
#pragma unroll
        for (int p = 0; p < 8; p++) {
            int e   = p * 256 + t;
            int row = e >> 4;
            int col = (e & 15) * 4;
            float4 fa = *(const float4*)&y[(size_t)(m0 + row) * C_ + k0 + col];
            ushort4 ua;
            ua.x = f2bf(fa.x); ua.y = f2bf(fa.y);
            ua.z = f2bf(fa.z); ua.w = f2bf(fa.w);
            *(ushort4*)&As[row][col] = ua;
            float4 fw = *(const float4*)&wproj[(size_t)row * C_ + k0 + col];
            ushort4 uw;
            uw.x = f2bf(fw.x); uw.y = f2bf(fw.y);
            uw.z = f2bf(fw.z); uw.w = f2bf(fw.w);
            *(ushort4*)&Ws[row][col] = uw;
        }
        __syncthreads();
#pragma unroll
        for (int kk = 0; kk < 2; kk++) {
            bf16x8 a[4], b[4];
#pragma unroll
            for (int mi = 0; mi < 4; mi++)
                a[mi] = *(const bf16x8*)&As[wm + mi * 16 + lr][kk * 32 + quad * 8];
#pragma unroll
            for (int ni = 0; ni < 4; ni++)
                b[ni] = *(const bf16x8*)&Ws[wn + ni * 16 + lr][kk * 32 + quad * 8];
#pragma unroll
            for (int mi = 0; mi < 4; mi++)
#pragma unroll
                for (int ni = 0; ni < 4; ni++)
                    acc[mi][ni] = __builtin_amdgcn_mfma_f32_16x16x32_bf16(
                        a[mi], b[ni], acc[mi][ni], 0, 0, 0);
        }
        if (kt == 0) __syncthreads();
    }

#pragma unroll
    for (int mi = 0; mi < 4; mi++) {
#pragma unroll
        for (int r = 0; r < 4; r++) {
            int m = m0 + wm + mi * 16 + quad * 4 + r;
#pragma unroll
            for (int ni = 0; ni < 4; ni++) {
                int c = wn + ni * 16 + lr;
                y[(size_t)m * C_ + c] = acc[mi][ni][r] + bproj[c];
            }
        }
    }
}

extern "C" void kernel_launch(void* const* d_in, const int* in_sizes, int n_in,
                              void* d_out, int out_size, void* d_ws, size_t ws_size,
                              hipStream_t stream)
{
    const float* x     = (const float*)d_in[0];
    const float* wqkv  = (const float*)d_in[1];
    const float* wlim  = (const float*)d_in[2];
    const float* blim  = (const float*)d_in[3];
    const float* wproj = (const float*)d_in[4];
    const float* bproj = (const float*)d_in[5];
    float* out = (float*)d_out;
    u16*   v   = (u16*)d_ws;            // 51.4 MB bf16 image-layout v

    ka_fused<<<dim3(B_ * 64), 256, 0, stream>>>(x, wqkv, v, out);
    kb_lim  <<<dim3(MM / 16), 256, 0, stream>>>(v, wlim, blim, out);
    kc_proj <<<dim3(MM / 128), 256, 0, stream>>>(out, wproj, bproj);
}

// Round 3
// 386.057 us; speedup vs baseline: 1.5110x; 1.1400x over previous
//
#include <hip/hip_runtime.h>
#include <cstdint>

#define B_   64
#define H_   56
#define W_   56
#define C_   128
#define WSZ  7
#define TT   49
#define NN   3136            // H*W
#define MM   (B_ * NN)       // 200704
#define SCALE 0.17677669529663687f

typedef short bf16x8 __attribute__((ext_vector_type(8)));   // 8 bf16 (4 VGPRs)
typedef short bf16x4 __attribute__((ext_vector_type(4)));   // 8B (2 VGPRs)
typedef float f32x4  __attribute__((ext_vector_type(4)));
typedef unsigned short u16;

__device__ __forceinline__ float bf2f(u16 u) {
    return __uint_as_float(((unsigned int)u) << 16);
}
__device__ __forceinline__ u16 f2bf(float f) {
    unsigned int u = __float_as_uint(f);
    u += 0x7FFFu + ((u >> 16) & 1u);   // round-to-nearest-even
    return (u16)(u >> 16);
}

// ---------------------------------------------------------------------------
// KW: one-shot f32 -> bf16 weight conversion into workspace tail.
//   wqbf[384*128]: w_qkv rows, with SCALE folded into the q rows (<128)
//   wpbf[128*128]: w_proj
// 64 blocks x 256 thr, one float4 group per thread (~4 us, launch-dominated).
// Removes ~670 VALU-inst/wave of per-block f2bf from ka (27% of its VALU)
// and 224 VALU/thread from kc.
// ---------------------------------------------------------------------------
__global__ __launch_bounds__(256) void kw_cvt(
    const float* __restrict__ wqkv, const float* __restrict__ wproj,
    u16* __restrict__ wqbf, u16* __restrict__ wpbf)
{
    int g = blockIdx.x * 256 + threadIdx.x;      // 16384 float4 groups
    if (g < 12288) {                             // w_qkv: 49152 elems
        float4 f = *(const float4*)&wqkv[g * 4];
        float mul = (g < 4096) ? SCALE : 1.0f;   // q rows get SCALE folded
        ushort4 u;
        u.x = f2bf(f.x * mul); u.y = f2bf(f.y * mul);
        u.z = f2bf(f.z * mul); u.w = f2bf(f.w * mul);
        *(ushort4*)&wqbf[g * 4] = u;
    } else {                                     // w_proj: 16384 elems
        int g2 = g - 12288;
        float4 f = *(const float4*)&wproj[g2 * 4];
        ushort4 u;
        u.x = f2bf(f.x); u.y = f2bf(f.y);
        u.z = f2bf(f.z); u.w = f2bf(f.w);
        *(ushort4*)&wpbf[g2 * 4] = u;
    }
}

// ---------------------------------------------------------------------------
// KA v4: fused qkv-GEMM + windowed attention, MFMA. One block per (b,window).
// LDS: 3 slabs (52,480 B -> 3 blocks/CU = 12 waves/CU):
//   xq[64][136]  x window, later overwritten by q (x dead after q-MFMA)
//   ks[64][136]  k
//   vs[64][138]  v  (stride 138: transpose reads conflict-free)
// P overlay: 256 x 68 u16 = 34,816 B == xq+ks exactly (barrier-protected).
// PREW=true: B-fragments are single 16B bf16x8 loads from precomputed wqbf
// (SCALE already folded into q rows) -- no f2bf on the MFMA dep chain.
// PREW=false: legacy f32-load + f2bf path (workspace-too-small fallback).
// ---------------------------------------------------------------------------
template <bool PREW>
__global__ __launch_bounds__(256, 3) void ka_fused(
    const float* __restrict__ x, const float* __restrict__ wqkv,
    const u16* __restrict__ wqbf,
    u16* __restrict__ vout, float* __restrict__ out)
{
    __shared__ u16 lds[26240];                       // 52,480 B
    u16 (*xq)[136] = (u16(*)[136])&lds[0];           // x, later q
    u16 (*ks)[136] = (u16(*)[136])&lds[8704];        // k
    u16 (*vs)[138] = (u16(*)[138])&lds[17408];       // v
    u16* ps_ = &lds[0];                              // P: 256 x 68 u16 overlay

    const int t   = threadIdx.x;
    const int blk = blockIdx.x;
    const int b_  = blk >> 6, wr = blk & 63;
    const int qy  = wr >> 3, qx = wr & 7;
    const int wave = t >> 6, lane = t & 63, lr = lane & 15, quad = lane >> 4;

    // ---- phase 0: stage x window -> xq (bf16), zero pad rows ----
    for (int i = t; i < 64 * 32; i += 256) {
        int tok = i >> 5, c4 = (i & 31) * 4;
        ushort4 u4 = {0, 0, 0, 0};
        if (tok < TT) {
            int hh = qy * WSZ + tok / WSZ, ww = qx * WSZ + tok % WSZ;
            float4 f = *(const float4*)&x[((size_t)b_ * NN + hh * W_ + ww) * C_ + c4];
            u4.x = f2bf(f.x); u4.y = f2bf(f.y);
            u4.z = f2bf(f.z); u4.w = f2bf(f.w);
        }
        *(ushort4*)&xq[tok][c4] = u4;
    }
    __syncthreads();

    // ---- phase 1a: k (ch=1) -> ks, v (ch=2) -> vs + global.
    // Each wave owns output cols [half*64+wave*16, +16) -> no barriers. ----
#pragma unroll
    for (int cc = 0; cc < 2; cc++) {
        const int ch = 1 + cc;
        u16* dstbase = cc ? &vs[0][0] : &ks[0][0];
        const int dstride = cc ? 138 : 136;
#pragma unroll
        for (int half = 0; half < 2; half++) {
            const int wrowi = ch * 128 + half * 64 + wave * 16 + lr;
            const float* wrowf = &wqkv[(size_t)wrowi * C_];
            const u16*   wrowb = &wqbf[(size_t)wrowi * C_];
            f32x4 acc[4];
#pragma unroll
            for (int mi = 0; mi < 4; mi++) acc[mi] = {0.f, 0.f, 0.f, 0.f};
#pragma unroll
            for (int kk = 0; kk < 4; kk++) {
                bf16x8 bfr;
                if constexpr (PREW) {
                    bfr = *(const bf16x8*)&wrowb[kk * 32 + quad * 8];
                } else {
                    float4 f0 = *(const float4*)&wrowf[kk * 32 + quad * 8];
                    float4 f1 = *(const float4*)&wrowf[kk * 32 + quad * 8 + 4];
                    bfr[0] = (short)f2bf(f0.x); bfr[1] = (short)f2bf(f0.y);
                    bfr[2] = (short)f2bf(f0.z); bfr[3] = (short)f2bf(f0.w);
                    bfr[4] = (short)f2bf(f1.x); bfr[5] = (short)f2bf(f1.y);
                    bfr[6] = (short)f2bf(f1.z); bfr[7] = (short)f2bf(f1.w);
                }
#pragma unroll
                for (int mi = 0; mi < 4; mi++) {
                    bf16x8 afr = *(const bf16x8*)&xq[mi * 16 + lr][kk * 32 + quad * 8];
                    acc[mi] = __builtin_amdgcn_mfma_f32_16x16x32_bf16(
                        afr, bfr, acc[mi], 0, 0, 0);
                }
            }
#pragma unroll
            for (int mi = 0; mi < 4; mi++) {
#pragma unroll
                for (int r = 0; r < 4; r++) {
                    int tok = mi * 16 + quad * 4 + r;
                    int col = half * 64 + wave * 16 + lr;
                    u16 bv = f2bf(acc[mi][r]);
                    dstbase[tok * dstride + col] = bv;
                    if (cc == 1 && tok < TT) {
                        int hh2 = qy * WSZ + tok / WSZ;
                        int ww2 = qx * WSZ + tok % WSZ;
                        vout[((size_t)b_ * NN + hh2 * W_ + ww2) * C_ + col] = bv;
                    }
                }
            }
        }
    }

    // ---- phase 1b: q accumulators in registers (x still live) ----
    const float qmul = PREW ? 1.0f : SCALE;      // SCALE folded into wqbf
    f32x4 qacc[2][4];
#pragma unroll
    for (int half = 0; half < 2; half++)
#pragma unroll
        for (int mi = 0; mi < 4; mi++) qacc[half][mi] = {0.f, 0.f, 0.f, 0.f};
#pragma unroll
    for (int half = 0; half < 2; half++) {
        const int wrowi = half * 64 + wave * 16 + lr;
        const float* wrowf = &wqkv[(size_t)wrowi * C_];
        const u16*   wrowb = &wqbf[(size_t)wrowi * C_];
#pragma unroll
        for (int kk = 0; kk < 4; kk++) {
            bf16x8 bfr;
            if constexpr (PREW) {
                bfr = *(const bf16x8*)&wrowb[kk * 32 + quad * 8];
            } else {
                float4 f0 = *(const float4*)&wrowf[kk * 32 + quad * 8];
                float4 f1 = *(const float4*)&wrowf[kk * 32 + quad * 8 + 4];
                bfr[0] = (short)f2bf(f0.x); bfr[1] = (short)f2bf(f0.y);
                bfr[2] = (short)f2bf(f0.z); bfr[3] = (short)f2bf(f0.w);
                bfr[4] = (short)f2bf(f1.x); bfr[5] = (short)f2bf(f1.y);
                bfr[6] = (short)f2bf(f1.z); bfr[7] = (short)f2bf(f1.w);
            }
#pragma unroll
            for (int mi = 0; mi < 4; mi++) {
                bf16x8 afr = *(const bf16x8*)&xq[mi * 16 + lr][kk * 32 + quad * 8];
                qacc[half][mi] = __builtin_amdgcn_mfma_f32_16x16x32_bf16(
                    afr, bfr, qacc[half][mi], 0, 0, 0);
            }
        }
    }
    __syncthreads();   // all x reads done; k/v published

    // write q (scaled) over the x slab
#pragma unroll
    for (int half = 0; half < 2; half++)
#pragma unroll
        for (int mi = 0; mi < 4; mi++)
#pragma unroll
            for (int r = 0; r < 4; r++)
                xq[mi * 16 + quad * 4 + r][half * 64 + wave * 16 + lr] =
                    f2bf(qacc[half][mi][r] * qmul);
    __syncthreads();   // q published

    // ---- phase 2: attention, wave = head ----
    const int h = wave;
    bf16x8 qf[4], kf[4];
#pragma unroll
    for (int mi = 0; mi < 4; mi++) {
        qf[mi] = *(const bf16x8*)&xq[mi * 16 + lr][h * 32 + quad * 8];
        kf[mi] = *(const bf16x8*)&ks[mi * 16 + lr][h * 32 + quad * 8];
    }
    __syncthreads();   // all waves hold q/k frags -> ps overlay now safe

    f32x4 s[4][4];
#pragma unroll
    for (int mi = 0; mi < 4; mi++)
#pragma unroll
        for (int nj = 0; nj < 4; nj++) s[mi][nj] = {0.f, 0.f, 0.f, 0.f};
#pragma unroll
    for (int mi = 0; mi < 4; mi++)
#pragma unroll
        for (int nj = 0; nj < 4; nj++)
            s[mi][nj] = __builtin_amdgcn_mfma_f32_16x16x32_bf16(
                qf[mi], kf[nj], s[mi][nj], 0, 0, 0);

    // mask pad key columns j = 48 + lr, lr >= 1
    if (lr >= 1) {
#pragma unroll
        for (int mi = 0; mi < 4; mi++)
#pragma unroll
            for (int r = 0; r < 4; r++) s[mi][3][r] = -1e30f;
    }

    float rsum[4][4];
#pragma unroll
    for (int mi = 0; mi < 4; mi++) {
#pragma unroll
        for (int r = 0; r < 4; r++) {
            float mx = fmaxf(fmaxf(s[mi][0][r], s[mi][1][r]),
                             fmaxf(s[mi][2][r], s[mi][3][r]));
#pragma unroll
            for (int off = 1; off < 16; off <<= 1)
                mx = fmaxf(mx, __shfl_xor(mx, off));
            float sum = 0.f;
#pragma unroll
            for (int nj = 0; nj < 4; nj++) {
                float p = __expf(s[mi][nj][r] - mx);
                s[mi][nj][r] = p;
                sum += p;
            }
#pragma unroll
            for (int off = 1; off < 16; off <<= 1)
                sum += __shfl_xor(sum, off);
            rsum[mi][r] = sum;
        }
    }

    // P: C-layout -> LDS (overlay, stride 68 = conflict-free) -> A-layout
#pragma unroll
    for (int mi = 0; mi < 4; mi++)
#pragma unroll
        for (int nj = 0; nj < 4; nj++)
#pragma unroll
            for (int r = 0; r < 4; r++)
                ps_[((h * 64) + mi * 16 + quad * 4 + r) * 68 + nj * 16 + lr] =
                    f2bf(s[mi][nj][r]);

    f32x4 o[4][2];
#pragma unroll
    for (int mi = 0; mi < 4; mi++)
#pragma unroll
        for (int nv = 0; nv < 2; nv++) o[mi][nv] = {0.f, 0.f, 0.f, 0.f};

#pragma unroll
    for (int kt = 0; kt < 2; kt++) {
        bf16x8 pf[4];
#pragma unroll
        for (int mi = 0; mi < 4; mi++) {
            const u16* pp = &ps_[((h * 64) + mi * 16 + lr) * 68 + kt * 32 + quad * 8];
            bf16x4 lo = *(const bf16x4*)&pp[0];    // 8B-aligned (rows stride 136B)
            bf16x4 hi = *(const bf16x4*)&pp[4];
            bf16x8 f;
            f[0] = lo[0]; f[1] = lo[1]; f[2] = lo[2]; f[3] = lo[3];
            f[4] = hi[0]; f[5] = hi[1]; f[6] = hi[2]; f[7] = hi[3];
            pf[mi] = f;
        }
        bf16x8 vf[2];
#pragma unroll
        for (int nv = 0; nv < 2; nv++) {
            bf16x8 tmp;
#pragma unroll
            for (int jj = 0; jj < 8; jj++)
                tmp[jj] = (short)vs[kt * 32 + quad * 8 + jj][h * 32 + nv * 16 + lr];
            vf[nv] = tmp;
        }
#pragma unroll
        for (int mi = 0; mi < 4; mi++)
#pragma unroll
            for (int nv = 0; nv < 2; nv++)
                o[mi][nv] = __builtin_amdgcn_mfma_f32_16x16x32_bf16(
                    pf[mi], vf[nv], o[mi][nv], 0, 0, 0);
    }

#pragma unroll
    for (int mi = 0; mi < 4; mi++) {
#pragma unroll
        for (int r = 0; r < 4; r++) {
            int i = mi * 16 + quad * 4 + r;
            if (i < TT) {
                int hh = qy * WSZ + i / WSZ, ww = qx * WSZ + i % WSZ;
                size_t orow = (size_t)b_ * NN + hh * W_ + ww;
                float inv = 1.f / rsum[mi][r];
#pragma unroll
                for (int nv = 0; nv < 2; nv++)
                    out[orow * C_ + h * 32 + nv * 16 + lr] = o[mi][nv][r] * inv;
            }
        }
    }
}

// ---------------------------------------------------------------------------
// KB v2: depthwise 3x3 conv on bf16 v (IMAGE layout B,H,W,C) + f32 bias,
// accumulate f32 into d_out (B,N,C). One thread = 8 channels of one position.
// ---------------------------------------------------------------------------
__global__ __launch_bounds__(256) void kb_lim(
    const u16* __restrict__ v, const float* __restrict__ wlim,
    const float* __restrict__ blim, float* __restrict__ out)
{
    const int t   = threadIdx.x;
    const int pos = blockIdx.x * 16 + (t >> 4);
    const int c0  = (t & 15) * 8;
    const int b_  = pos / NN;
    const int rem = pos - b_ * NN;
    const int hh  = rem / W_;
    const int ww  = rem - hh * W_;

    float w72[72];
    {
        const float* wp = &wlim[c0 * 9];
#pragma unroll
        for (int i = 0; i < 18; i++) {
            float4 f = *(const float4*)&wp[i * 4];
            w72[i * 4 + 0] = f.x; w72[i * 4 + 1] = f.y;
            w72[i * 4 + 2] = f.z; w72[i * 4 + 3] = f.w;
        }
    }
    float acc[8];
    {
        float4 b0 = *(const float4*)&blim[c0];
        float4 b1 = *(const float4*)&blim[c0 + 4];
        acc[0] = b0.x; acc[1] = b0.y; acc[2] = b0.z; acc[3] = b0.w;
        acc[4] = b1.x; acc[5] = b1.y; acc[6] = b1.z; acc[7] = b1.w;
    }

    const u16* vbase = &v[(size_t)b_ * NN * C_ + c0];
#pragma unroll
    for (int dy = -1; dy <= 1; dy++) {
        int y = hh + dy;
        bool yok = (unsigned)y < (unsigned)H_;
#pragma unroll
        for (int dx = -1; dx <= 1; dx++) {
            int x2 = ww + dx;
            bool ok = yok && ((unsigned)x2 < (unsigned)W_);
            bf16x8 vv = {0, 0, 0, 0, 0, 0, 0, 0};
            if (ok) vv = *(const bf16x8*)&vbase[(size_t)(y * W_ + x2) * C_];
            const int tap = (dy + 1) * 3 + (dx + 1);
#pragma unroll
            for (int j = 0; j < 8; j++)
                acc[j] += bf2f((u16)vv[j]) * w72[j * 9 + tap];
        }
    }

    float* op = &out[(size_t)pos * C_ + c0];
    float4 o0 = *(const float4*)&op[0];
    float4 o1 = *(const float4*)&op[4];
    o0.x += acc[0]; o0.y += acc[1]; o0.z += acc[2]; o0.w += acc[3];
    o1.x += acc[4]; o1.y += acc[5]; o1.z += acc[6]; o1.w += acc[7];
    *(float4*)&op[0] = o0;
    *(float4*)&op[4] = o1;
}

// ---------------------------------------------------------------------------
// KC: out = y @ w_proj^T + b_proj, MFMA gemm_bt, f32 I/O staged to bf16.
// PREW=true: Ws staged by direct 16B bf16 copies from precomputed wpbf
// (saves 16 float4 loads + 64 f2bf per thread).
// ---------------------------------------------------------------------------
template <bool PREW>
__global__ __launch_bounds__(256) void kc_proj(
    float* __restrict__ y, const float* __restrict__ wproj,
    const u16* __restrict__ wpbf, const float* __restrict__ bproj)
{
    __shared__ u16 As[128][72];
    __shared__ u16 Ws[128][72];
    const int t    = threadIdx.x;
    const int m0   = blockIdx.x * 128;
    const int wave = t >> 6, lane = t & 63, lr = lane & 15, quad = lane >> 4;
    const int wm = (wave >> 1) * 64, wn = (wave & 1) * 64;

    f32x4 acc[4][4];
#pragma unroll
    for (int mi = 0; mi < 4; mi++)
#pragma unroll
        for (int ni = 0; ni < 4; ni++) acc[mi][ni] = {0.f, 0.f, 0.f, 0.f};

#pragma unroll
    for (int kt = 0; kt < 2; kt++) {
        const int k0 = kt * 64;
#pragma unroll
        for (int p = 0; p < 8; p++) {
            int e   = p * 256 + t;
            int row = e >> 4;
            int col = (e & 15) * 4;
            float4 fa = *(const float4*)&y[(size_t)(m0 + row) * C_ + k0 + col];
            ushort4 ua;
            ua.x = f2bf(fa.x); ua.y = f2bf(fa.y);
            ua.z = f2bf(fa.z); ua.w = f2bf(fa.w);
            *(ushort4*)&As[row][col] = ua;
            if constexpr (!PREW) {
                float4 fw = *(const float4*)&wproj[(size_t)row * C_ + k0 + col];
                ushort4 uw;
                uw.x = f2bf(fw.x); uw.y = f2bf(fw.y);
                uw.z = f2bf(fw.z); uw.w = f2bf(fw.w);
                *(ushort4*)&Ws[row][col] = uw;
            }
        }
        if constexpr (PREW) {
#pragma unroll
            for (int p4 = 0; p4 < 4; p4++) {
                int e    = p4 * 256 + t;
                int row  = e >> 3;
                int col8 = (e & 7) * 8;
                *(bf16x8*)&Ws[row][col8] =
                    *(const bf16x8*)&wpbf[(size_t)row * C_ + k0 + col8];
            }
        }
        __syncthreads();
#pragma unroll
        for (int kk = 0; kk < 2; kk++) {
            bf16x8 a[4], b[4];
#pragma unroll
            for (int mi = 0; mi < 4; mi++)
                a[mi] = *(const bf16x8*)&As[wm + mi * 16 + lr][kk * 32 + quad * 8];
#pragma unroll
            for (int ni = 0; ni < 4; ni++)
                b[ni] = *(const bf16x8*)&Ws[wn + ni * 16 + lr][kk * 32 + quad * 8];
#pragma unroll
            for (int mi = 0; mi < 4; mi++)
#pragma unroll
                for (int ni = 0; ni < 4; ni++)
                    acc[mi][ni] = __builtin_amdgcn_mfma_f32_16x16x32_bf16(
                        a[mi], b[ni], acc[mi][ni], 0, 0, 0);
        }
        if (kt == 0) __syncthreads();
    }

#pragma unroll
    for (int mi = 0; mi < 4; mi++) {
#pragma unroll
        for (int r = 0; r < 4; r++) {
            int m = m0 + wm + mi * 16 + quad * 4 + r;
#pragma unroll
            for (int ni = 0; ni < 4; ni++) {
                int c = wn + ni * 16 + lr;
                y[(size_t)m * C_ + c] = acc[mi][ni][r] + bproj[c];
            }
        }
    }
}

extern "C" void kernel_launch(void* const* d_in, const int* in_sizes, int n_in,
                              void* d_out, int out_size, void* d_ws, size_t ws_size,
                              hipStream_t stream)
{
    const float* x     = (const float*)d_in[0];
    const float* wqkv  = (const float*)d_in[1];
    const float* wlim  = (const float*)d_in[2];
    const float* blim  = (const float*)d_in[3];
    const float* wproj = (const float*)d_in[4];
    const float* bproj = (const float*)d_in[5];
    float* out = (float*)d_out;
    u16*   v   = (u16*)d_ws;                       // 51,380,224 B bf16 image v

    const size_t vbytes = (size_t)MM * C_ * 2;     // 51,380,224 (256B-aligned)
    const size_t need   = vbytes + (49152 + 16384) * 2;   // +131,072

    if (ws_size >= need) {
        u16* wqbf = (u16*)((char*)d_ws + vbytes);
        u16* wpbf = wqbf + 49152;
        kw_cvt<<<dim3(64), 256, 0, stream>>>(wqkv, wproj, wqbf, wpbf);
        ka_fused<true><<<dim3(B_ * 64), 256, 0, stream>>>(x, wqkv, wqbf, v, out);
        kb_lim  <<<dim3(MM / 16), 256, 0, stream>>>(v, wlim, blim, out);
        kc_proj<true><<<dim3(MM / 128), 256, 0, stream>>>(out, wproj, wpbf, bproj);
    } else {
        ka_fused<false><<<dim3(B_ * 64), 256, 0, stream>>>(x, wqkv, nullptr, v, out);
        kb_lim  <<<dim3(MM / 16), 256, 0, stream>>>(v, wlim, blim, out);
        kc_proj<false><<<dim3(MM / 128), 256, 0, stream>>>(out, wproj, nullptr, bproj);
    }
}